// Round 7
// baseline (184.835 us; speedup 1.0000x reference)
//
#include <hip/hip_runtime.h>

#define NPTS 1000000
#define OUT_STRIDE (9 * NPTS)

// Scales order: [2, 4, 8, 16, 1]; dims = ceil(SPATIAL/scale)+1
constexpr int   kSX[5]  = {241, 121, 61, 31, 481};
constexpr int   kSY[5]  = {181,  91, 46, 24, 361};
constexpr int   kSZ[5]  = { 17,   9,  5,  3,  33};
constexpr float kSSX[5] = {240.f, 120.f, 60.f, 30.f, 480.f};
constexpr float kSSY[5] = {180.f,  90.f, 45.f, 23.f, 360.f};
constexpr float kSSZ[5] = { 16.f,   8.f,  4.f,  2.f,  32.f};
// word-bases of each scale's bitmap region (keyspace/32, rounded up to 64)
constexpr int kWB[5] = {0, 92736, 105152, 106944, 107264};
#define W_TOTAL 823552        // 107264 + 716288
#define SCAN_BLOCKS 403       // ceil(W_TOTAL / 2048)

// byte map = exact 32x expansion of the bit map: byte index = word*32 + bit.
#define BM_BYTES ((size_t)W_TOTAL * 32)     // 26,353,664 B
#define BM_U4    (BM_BYTES / 16)            // 1,647,104 uint4

// emit kernel block ranges (256 threads each)
#define SCAT_BLOCKS 3217    // ceil(W_TOTAL / 256)
#define PAD_BLOCKS  19532   // ceil(5*NPTS / 256)
#define INV_BLOCKS  3907    // ceil(NPTS / 256)
#define EMIT_BLOCKS (SCAT_BLOCKS + PAD_BLOCKS + INV_BLOCKS)

typedef int v4i __attribute__((ext_vector_type(4)));
__device__ __forceinline__ void nt_store4(int* p, int a, int b, int c, int d) {
  v4i v = {a, b, c, d};
  __builtin_nontemporal_store(v, (v4i*)p);
}

// ---- zero the byte map + the ticket word
__global__ void zero_kernel(uint4* __restrict__ p, unsigned* __restrict__ ticket) {
  size_t i = (size_t)blockIdx.x * 256 + threadIdx.x;
  if (i < BM_U4) p[i] = make_uint4(0u, 0u, 0u, 0u);
  if (i == 0) *ticket = 0u;
}

// ---- mark: polar once per point; bxyz out (nt); 5 idempotent byte stores
__global__ void mark_kernel(const float4* __restrict__ pts,
                            const int* __restrict__ bidx,
                            int* __restrict__ out,
                            unsigned char* __restrict__ bytemap) {
  int i = blockIdx.x * 256 + threadIdx.x;
  if (i >= NPTS) return;
  float4 p = pts[i];
  float rho = __fsqrt_rn(__fadd_rn(__fmul_rn(p.x, p.x), __fmul_rn(p.y, p.y)));
  float phi = (float)atan2((double)p.y, (double)p.x);
  float zz = p.z;
  int b = bidx[i];
  const float PI_F = 3.14159265f;
  const float CROP1 = PI_F + PI_F;
#pragma unroll
  for (int s = 0; s < 5; ++s) {
    int ix = (int)__fdiv_rn(__fmul_rn(kSSX[s], rho), 50.0f);
    int iy = (int)__fdiv_rn(__fmul_rn(kSSY[s], __fsub_rn(phi, -PI_F)), CROP1);
    int iz = (int)__fdiv_rn(__fmul_rn(kSSZ[s], __fsub_rn(zz, -4.0f)), 6.0f);
    int key = ((b * kSX[s] + ix) * kSY[s] + iy) * kSZ[s] + iz;
    nt_store4(out + (size_t)s * OUT_STRIDE + (size_t)i * 4, b, ix, iy, iz);
    bytemap[(size_t)kWB[s] * 32 + (unsigned)key] = 1;
  }
}

// 32 presence-bytes (each 0/1) -> 32-bit mask
__device__ __forceinline__ unsigned nib(unsigned u) {
  return (u | (u >> 7) | (u >> 14) | (u >> 21)) & 0xFu;
}
__device__ __forceinline__ unsigned word_from_bytes(const uint4* p) {
  uint4 a = p[0], b = p[1];
  return nib(a.x) | (nib(a.y) << 4) | (nib(a.z) << 8) | (nib(a.w) << 12) |
         (nib(b.x) << 16) | (nib(b.y) << 20) | (nib(b.z) << 24) | (nib(b.w) << 28);
}

// ---- fused scan: bytes->bits + per-chunk prefix; LAST block scans chunk sums
__global__ void scan_kernel(const uint4* __restrict__ bytemap,
                            unsigned* __restrict__ bits,
                            unsigned* __restrict__ wp,
                            unsigned* __restrict__ bsums,
                            unsigned* __restrict__ ticket) {
  __shared__ unsigned sh[256];
  __shared__ int amlast;
  int tid = threadIdx.x;
  int base = blockIdx.x * 2048 + tid * 8;
  unsigned c[8];
  unsigned sum = 0;
#pragma unroll
  for (int j = 0; j < 8; ++j) {
    c[j] = sum;
    int w = base + j;
    unsigned m = 0;
    if (w < W_TOTAL) {
      m = word_from_bytes(bytemap + (size_t)w * 2);
      bits[w] = m;
    }
    sum += (unsigned)__popc(m);
  }
  sh[tid] = sum;
  __syncthreads();
  for (int off = 1; off < 256; off <<= 1) {
    unsigned v = (tid >= off) ? sh[tid - off] : 0u;
    __syncthreads();
    sh[tid] += v;
    __syncthreads();
  }
  unsigned tbase = sh[tid] - sum;
#pragma unroll
  for (int j = 0; j < 8; ++j) {
    int w = base + j;
    if (w < W_TOTAL) wp[w] = tbase + c[j];
  }
  if (tid == 0) {
    __hip_atomic_store(&bsums[blockIdx.x], sh[255], __ATOMIC_RELEASE,
                       __HIP_MEMORY_SCOPE_AGENT);
    unsigned t = __hip_atomic_fetch_add(ticket, 1u, __ATOMIC_ACQ_REL,
                                        __HIP_MEMORY_SCOPE_AGENT);
    amlast = (t == SCAN_BLOCKS - 1);
  }
  __syncthreads();
  if (!amlast) return;
  // last-arriving block: exclusive-scan the 403 chunk sums (2 per thread)
  int i0 = tid * 2, i1 = tid * 2 + 1;
  unsigned e0 = (i0 < SCAN_BLOCKS)
      ? __hip_atomic_load(&bsums[i0], __ATOMIC_ACQUIRE, __HIP_MEMORY_SCOPE_AGENT) : 0u;
  unsigned e1 = (i1 < SCAN_BLOCKS)
      ? __hip_atomic_load(&bsums[i1], __ATOMIC_ACQUIRE, __HIP_MEMORY_SCOPE_AGENT) : 0u;
  unsigned s2 = e0 + e1;
  __syncthreads();          // sh[] reuse
  sh[tid] = s2;
  __syncthreads();
  for (int off = 1; off < 256; off <<= 1) {
    unsigned v = (tid >= off) ? sh[tid - off] : 0u;
    __syncthreads();
    sh[tid] += v;
    __syncthreads();
  }
  unsigned ebase = sh[tid] - s2;   // exclusive over pairs
  if (i0 < SCAN_BLOCKS) bsums[i0] = ebase;
  if (i1 < SCAN_BLOCKS) bsums[i1] = ebase + e0;
  if (tid == 255) bsums[512] = sh[255];   // grand total
}

// full prefix of word w = wp[w] + bsums[w >> 11]
__device__ __forceinline__ unsigned fullp(const unsigned* wp, const unsigned* bs, int w) {
  return wp[w] + bs[w >> 11];
}

__device__ __forceinline__ unsigned region_count(int s, const unsigned* wp,
                                                 const unsigned* bs) {
  unsigned lo = fullp(wp, bs, kWB[s]);
  unsigned hi = (s == 4) ? bs[512] : fullp(wp, bs, kWB[s + 1]);
  return hi - lo;
}

// ---- emit: fused scatter / padfill / inverse (all nt stores to out)
__global__ void emit_kernel(const float4* __restrict__ pts,
                            const int* __restrict__ bidx,
                            const unsigned* __restrict__ bits,
                            const unsigned* __restrict__ wp,
                            const unsigned* __restrict__ bsums,
                            int* __restrict__ out) {
  int blk = blockIdx.x;
  if (blk < SCAT_BLOCKS) {
    int w = blk * 256 + threadIdx.x;
    if (w >= W_TOTAL) return;
    unsigned word = bits[w];
    if (!word) return;
    int s, wb;
    unsigned sx, sy, sz;
    if      (w >= kWB[4]) { s = 4; wb = kWB[4]; sx = 481; sy = 361; sz = 33; }
    else if (w >= kWB[3]) { s = 3; wb = kWB[3]; sx = 31;  sy = 24;  sz = 3;  }
    else if (w >= kWB[2]) { s = 2; wb = kWB[2]; sx = 61;  sy = 46;  sz = 5;  }
    else if (w >= kWB[1]) { s = 1; wb = kWB[1]; sx = 121; sy = 91;  sz = 9;  }
    else                  { s = 0; wb = 0;      sx = 241; sy = 181; sz = 17; }
    unsigned rank = fullp(wp, bsums, w) - fullp(wp, bsums, wb);
    int* coors = out + (size_t)s * OUT_STRIDE + 5 * NPTS;
    unsigned kbase = (unsigned)(w - wb) * 32u;
    while (word) {
      int bit = __ffs(word) - 1;
      word &= word - 1;
      unsigned k = kbase + (unsigned)bit;
      unsigned z = k % sz; unsigned t = k / sz;
      unsigned y = t % sy; t /= sy;
      unsigned x = t % sx; unsigned b = t / sx;
      nt_store4(coors + (size_t)rank * 4, (int)b, (int)z, (int)y, (int)x);
      rank++;
    }
  } else if (blk < SCAT_BLOCKS + PAD_BLOCKS) {
    int idx = (blk - SCAT_BLOCKS) * 256 + threadIdx.x;
    if (idx >= 5 * NPTS) return;
    int s = idx / NPTS;
    int r = idx - s * NPTS;
    unsigned uniq = region_count(s, wp, bsums);
    if ((unsigned)r < uniq) return;
    nt_store4(out + (size_t)s * OUT_STRIDE + 5 * NPTS + (size_t)r * 4,
              -1, kSZ[s] - 1, kSY[s] - 1, kSX[s] - 1);
  } else {
    int i = (blk - SCAT_BLOCKS - PAD_BLOCKS) * 256 + threadIdx.x;
    if (i >= NPTS) return;
    float4 p = pts[i];
    float rho = __fsqrt_rn(__fadd_rn(__fmul_rn(p.x, p.x), __fmul_rn(p.y, p.y)));
    float phi = (float)atan2((double)p.y, (double)p.x);
    float zz = p.z;
    int b = bidx[i];
    const float PI_F = 3.14159265f;
    const float CROP1 = PI_F + PI_F;
#pragma unroll
    for (int s = 0; s < 5; ++s) {
      int ix = (int)__fdiv_rn(__fmul_rn(kSSX[s], rho), 50.0f);
      int iy = (int)__fdiv_rn(__fmul_rn(kSSY[s], __fsub_rn(phi, -PI_F)), CROP1);
      int iz = (int)__fdiv_rn(__fmul_rn(kSSZ[s], __fsub_rn(zz, -4.0f)), 6.0f);
      unsigned k = (unsigned)(((b * kSX[s] + ix) * kSY[s] + iy) * kSZ[s] + iz);
      int w = kWB[s] + (int)(k >> 5);
      unsigned r = fullp(wp, bsums, w) - fullp(wp, bsums, kWB[s]) +
                   (unsigned)__popc(bits[w] & ((1u << (k & 31)) - 1u));
      __builtin_nontemporal_store((int)r, out + (size_t)s * OUT_STRIDE + 4 * NPTS + i);
    }
  }
}

extern "C" void kernel_launch(void* const* d_in, const int* in_sizes, int n_in,
                              void* d_out, int out_size, void* d_ws, size_t ws_size,
                              hipStream_t stream) {
  const float4* pts = (const float4*)d_in[0];
  const int* bidx = (const int*)d_in[1];
  int* out = (int*)d_out;

  unsigned* bits   = (unsigned*)d_ws;         // W_TOTAL u32 (3.3 MB)
  unsigned* wp     = bits + W_TOTAL;          // W_TOTAL u32 (3.3 MB)
  unsigned* bsums  = wp + W_TOTAL;            // 1024 u32 ([512] = grand total)
  unsigned* ticket = bsums + 768;             // 1 u32 (inside bsums alloc, unused slot)
  unsigned char* bytemap = (unsigned char*)(bsums + 1024);  // 26.4 MB
  // total ws use: ~33 MB (proven available)

  zero_kernel<<<(int)((BM_U4 + 255) / 256), 256, 0, stream>>>((uint4*)bytemap, ticket);
  mark_kernel<<<(NPTS + 255) / 256, 256, 0, stream>>>(pts, bidx, out, bytemap);
  scan_kernel<<<SCAN_BLOCKS, 256, 0, stream>>>((const uint4*)bytemap, bits, wp,
                                               bsums, ticket);
  emit_kernel<<<EMIT_BLOCKS, 256, 0, stream>>>(pts, bidx, bits, wp, bsums, out);
}

// Round 8
// 147.571 us; speedup vs baseline: 1.2525x; 1.2525x over previous
//
#include <hip/hip_runtime.h>

#define NPTS 1000000
#define OUT_STRIDE (9 * NPTS)

// Scales order: [2, 4, 8, 16, 1]; dims = ceil(SPATIAL/scale)+1
constexpr int   kSX[5]  = {241, 121, 61, 31, 481};
constexpr int   kSY[5]  = {181,  91, 46, 24, 361};
constexpr int   kSZ[5]  = { 17,   9,  5,  3,  33};
constexpr float kSSX[5] = {240.f, 120.f, 60.f, 30.f, 480.f};
constexpr float kSSY[5] = {180.f,  90.f, 45.f, 23.f, 360.f};
constexpr float kSSZ[5] = { 16.f,   8.f,  4.f,  2.f,  32.f};
// word-bases of each scale's bitmap region (keyspace/32, rounded up to 64)
constexpr int kWB[5] = {0, 92736, 105152, 106944, 107264};
#define W_TOTAL 823552        // 107264 + 716288
#define SCAN_BLOCKS 403       // ceil(W_TOTAL / 2048)

// byte map = exact 32x expansion of the bit map: byte index = word*32 + bit.
#define BM_BYTES ((size_t)W_TOTAL * 32)     // 26,353,664 B
#define BM_U4    (BM_BYTES / 16)            // 1,647,104 uint4

// emit kernel block ranges (256 threads each)
#define SCAT_BLOCKS 3217    // ceil(W_TOTAL / 256)
#define PAD_BLOCKS  19532   // ceil(5*NPTS / 256)
#define INV_BLOCKS  3907    // ceil(NPTS / 256)
#define EMIT_BLOCKS (SCAT_BLOCKS + PAD_BLOCKS + INV_BLOCKS)

// ---- zero the byte map + the ticket word
__global__ void zero_kernel(uint4* __restrict__ p, unsigned* __restrict__ ticket) {
  size_t i = (size_t)blockIdx.x * 256 + threadIdx.x;
  if (i < BM_U4) p[i] = make_uint4(0u, 0u, 0u, 0u);
  if (i == 0) *ticket = 0u;
}

// ---- mark: polar once per point; bxyz out; 5 idempotent byte stores
__global__ void mark_kernel(const float4* __restrict__ pts,
                            const int* __restrict__ bidx,
                            int* __restrict__ out,
                            unsigned char* __restrict__ bytemap) {
  int i = blockIdx.x * 256 + threadIdx.x;
  if (i >= NPTS) return;
  float4 p = pts[i];
  float rho = __fsqrt_rn(__fadd_rn(__fmul_rn(p.x, p.x), __fmul_rn(p.y, p.y)));
  float phi = (float)atan2((double)p.y, (double)p.x);
  float zz = p.z;
  int b = bidx[i];
  const float PI_F = 3.14159265f;
  const float CROP1 = PI_F + PI_F;
#pragma unroll
  for (int s = 0; s < 5; ++s) {
    int ix = (int)__fdiv_rn(__fmul_rn(kSSX[s], rho), 50.0f);
    int iy = (int)__fdiv_rn(__fmul_rn(kSSY[s], __fsub_rn(phi, -PI_F)), CROP1);
    int iz = (int)__fdiv_rn(__fmul_rn(kSSZ[s], __fsub_rn(zz, -4.0f)), 6.0f);
    int key = ((b * kSX[s] + ix) * kSY[s] + iy) * kSZ[s] + iz;
    ((int4*)(out + (size_t)s * OUT_STRIDE))[i] = make_int4(b, ix, iy, iz);
    bytemap[(size_t)kWB[s] * 32 + (unsigned)key] = 1;
  }
}

// 32 presence-bytes (each 0/1) -> 32-bit mask
__device__ __forceinline__ unsigned nib(unsigned u) {
  return (u | (u >> 7) | (u >> 14) | (u >> 21)) & 0xFu;
}
__device__ __forceinline__ unsigned word_from_bytes(const uint4* p) {
  uint4 a = p[0], b = p[1];
  return nib(a.x) | (nib(a.y) << 4) | (nib(a.z) << 8) | (nib(a.w) << 12) |
         (nib(b.x) << 16) | (nib(b.y) << 20) | (nib(b.z) << 24) | (nib(b.w) << 28);
}

// ---- fused scan: bytes->bits + per-chunk prefix; LAST block scans chunk sums
__global__ void scan_kernel(const uint4* __restrict__ bytemap,
                            unsigned* __restrict__ bits,
                            unsigned* __restrict__ wp,
                            unsigned* __restrict__ bsums,
                            unsigned* __restrict__ ticket) {
  __shared__ unsigned sh[256];
  __shared__ int amlast;
  int tid = threadIdx.x;
  int base = blockIdx.x * 2048 + tid * 8;
  unsigned c[8];
  unsigned sum = 0;
#pragma unroll
  for (int j = 0; j < 8; ++j) {
    c[j] = sum;
    int w = base + j;
    unsigned m = 0;
    if (w < W_TOTAL) {
      m = word_from_bytes(bytemap + (size_t)w * 2);
      bits[w] = m;
    }
    sum += (unsigned)__popc(m);
  }
  sh[tid] = sum;
  __syncthreads();
  for (int off = 1; off < 256; off <<= 1) {
    unsigned v = (tid >= off) ? sh[tid - off] : 0u;
    __syncthreads();
    sh[tid] += v;
    __syncthreads();
  }
  unsigned tbase = sh[tid] - sum;
#pragma unroll
  for (int j = 0; j < 8; ++j) {
    int w = base + j;
    if (w < W_TOTAL) wp[w] = tbase + c[j];
  }
  if (tid == 0) {
    __hip_atomic_store(&bsums[blockIdx.x], sh[255], __ATOMIC_RELEASE,
                       __HIP_MEMORY_SCOPE_AGENT);
    unsigned t = __hip_atomic_fetch_add(ticket, 1u, __ATOMIC_ACQ_REL,
                                        __HIP_MEMORY_SCOPE_AGENT);
    amlast = (t == SCAN_BLOCKS - 1);
  }
  __syncthreads();
  if (!amlast) return;
  // last-arriving block: exclusive-scan the 403 chunk sums (2 per thread)
  int i0 = tid * 2, i1 = tid * 2 + 1;
  unsigned e0 = (i0 < SCAN_BLOCKS)
      ? __hip_atomic_load(&bsums[i0], __ATOMIC_ACQUIRE, __HIP_MEMORY_SCOPE_AGENT) : 0u;
  unsigned e1 = (i1 < SCAN_BLOCKS)
      ? __hip_atomic_load(&bsums[i1], __ATOMIC_ACQUIRE, __HIP_MEMORY_SCOPE_AGENT) : 0u;
  unsigned s2 = e0 + e1;
  __syncthreads();          // sh[] reuse
  sh[tid] = s2;
  __syncthreads();
  for (int off = 1; off < 256; off <<= 1) {
    unsigned v = (tid >= off) ? sh[tid - off] : 0u;
    __syncthreads();
    sh[tid] += v;
    __syncthreads();
  }
  unsigned ebase = sh[tid] - s2;   // exclusive over pairs
  if (i0 < SCAN_BLOCKS) bsums[i0] = ebase;
  if (i1 < SCAN_BLOCKS) bsums[i1] = ebase + e0;
  if (tid == 255) bsums[512] = sh[255];   // grand total
}

// full prefix of word w = wp[w] + bsums[w >> 11]
__device__ __forceinline__ unsigned fullp(const unsigned* wp, const unsigned* bs, int w) {
  return wp[w] + bs[w >> 11];
}

__device__ __forceinline__ unsigned region_count(int s, const unsigned* wp,
                                                 const unsigned* bs) {
  unsigned lo = fullp(wp, bs, kWB[s]);
  unsigned hi = (s == 4) ? bs[512] : fullp(wp, bs, kWB[s + 1]);
  return hi - lo;
}

// ---- emit: fused scatter / padfill / inverse
__global__ void emit_kernel(const float4* __restrict__ pts,
                            const int* __restrict__ bidx,
                            const unsigned* __restrict__ bits,
                            const unsigned* __restrict__ wp,
                            const unsigned* __restrict__ bsums,
                            int* __restrict__ out) {
  int blk = blockIdx.x;
  if (blk < SCAT_BLOCKS) {
    int w = blk * 256 + threadIdx.x;
    if (w >= W_TOTAL) return;
    unsigned word = bits[w];
    if (!word) return;
    int s, wb;
    unsigned sx, sy, sz;
    if      (w >= kWB[4]) { s = 4; wb = kWB[4]; sx = 481; sy = 361; sz = 33; }
    else if (w >= kWB[3]) { s = 3; wb = kWB[3]; sx = 31;  sy = 24;  sz = 3;  }
    else if (w >= kWB[2]) { s = 2; wb = kWB[2]; sx = 61;  sy = 46;  sz = 5;  }
    else if (w >= kWB[1]) { s = 1; wb = kWB[1]; sx = 121; sy = 91;  sz = 9;  }
    else                  { s = 0; wb = 0;      sx = 241; sy = 181; sz = 17; }
    unsigned rank = fullp(wp, bsums, w) - fullp(wp, bsums, wb);
    int4* coors = (int4*)(out + (size_t)s * OUT_STRIDE + 5 * NPTS);
    unsigned kbase = (unsigned)(w - wb) * 32u;
    while (word) {
      int bit = __ffs(word) - 1;
      word &= word - 1;
      unsigned k = kbase + (unsigned)bit;
      unsigned z = k % sz; unsigned t = k / sz;
      unsigned y = t % sy; t /= sy;
      unsigned x = t % sx; unsigned b = t / sx;
      coors[rank++] = make_int4((int)b, (int)z, (int)y, (int)x);
    }
  } else if (blk < SCAT_BLOCKS + PAD_BLOCKS) {
    int idx = (blk - SCAT_BLOCKS) * 256 + threadIdx.x;
    if (idx >= 5 * NPTS) return;
    int s = idx / NPTS;
    int r = idx - s * NPTS;
    unsigned uniq = region_count(s, wp, bsums);
    if ((unsigned)r < uniq) return;
    ((int4*)(out + (size_t)s * OUT_STRIDE + 5 * NPTS))[r] =
        make_int4(-1, kSZ[s] - 1, kSY[s] - 1, kSX[s] - 1);
  } else {
    int i = (blk - SCAT_BLOCKS - PAD_BLOCKS) * 256 + threadIdx.x;
    if (i >= NPTS) return;
    float4 p = pts[i];
    float rho = __fsqrt_rn(__fadd_rn(__fmul_rn(p.x, p.x), __fmul_rn(p.y, p.y)));
    float phi = (float)atan2((double)p.y, (double)p.x);
    float zz = p.z;
    int b = bidx[i];
    const float PI_F = 3.14159265f;
    const float CROP1 = PI_F + PI_F;
#pragma unroll
    for (int s = 0; s < 5; ++s) {
      int ix = (int)__fdiv_rn(__fmul_rn(kSSX[s], rho), 50.0f);
      int iy = (int)__fdiv_rn(__fmul_rn(kSSY[s], __fsub_rn(phi, -PI_F)), CROP1);
      int iz = (int)__fdiv_rn(__fmul_rn(kSSZ[s], __fsub_rn(zz, -4.0f)), 6.0f);
      unsigned k = (unsigned)(((b * kSX[s] + ix) * kSY[s] + iy) * kSZ[s] + iz);
      int w = kWB[s] + (int)(k >> 5);
      unsigned r = fullp(wp, bsums, w) - fullp(wp, bsums, kWB[s]) +
                   (unsigned)__popc(bits[w] & ((1u << (k & 31)) - 1u));
      out[(size_t)s * OUT_STRIDE + 4 * NPTS + i] = (int)r;
    }
  }
}

extern "C" void kernel_launch(void* const* d_in, const int* in_sizes, int n_in,
                              void* d_out, int out_size, void* d_ws, size_t ws_size,
                              hipStream_t stream) {
  const float4* pts = (const float4*)d_in[0];
  const int* bidx = (const int*)d_in[1];
  int* out = (int*)d_out;

  unsigned* bits   = (unsigned*)d_ws;         // W_TOTAL u32 (3.3 MB)
  unsigned* wp     = bits + W_TOTAL;          // W_TOTAL u32 (3.3 MB)
  unsigned* bsums  = wp + W_TOTAL;            // 1024 u32 ([512] = grand total)
  unsigned* ticket = bsums + 768;             // 1 u32 (inside bsums alloc, unused slot)
  unsigned char* bytemap = (unsigned char*)(bsums + 1024);  // 26.4 MB
  // total ws use: ~33 MB (proven available)

  zero_kernel<<<(int)((BM_U4 + 255) / 256), 256, 0, stream>>>((uint4*)bytemap, ticket);
  mark_kernel<<<(NPTS + 255) / 256, 256, 0, stream>>>(pts, bidx, out, bytemap);
  scan_kernel<<<SCAN_BLOCKS, 256, 0, stream>>>((const uint4*)bytemap, bits, wp,
                                               bsums, ticket);
  emit_kernel<<<EMIT_BLOCKS, 256, 0, stream>>>(pts, bidx, bits, wp, bsums, out);
}

// Round 9
// 109.216 us; speedup vs baseline: 1.6924x; 1.3512x over previous
//
#include <hip/hip_runtime.h>

#define NPTS 1000000
#define OUT_STRIDE (9 * NPTS)

// Scales order: [2, 4, 8, 16, 1]; dims = ceil(SPATIAL/scale)+1
constexpr int   kSX[5]  = {241, 121, 61, 31, 481};
constexpr int   kSY[5]  = {181,  91, 46, 24, 361};
constexpr int   kSZ[5]  = { 17,   9,  5,  3,  33};
constexpr float kSSX[5] = {240.f, 120.f, 60.f, 30.f, 480.f};
constexpr float kSSY[5] = {180.f,  90.f, 45.f, 23.f, 360.f};
constexpr float kSSZ[5] = { 16.f,   8.f,  4.f,  2.f,  32.f};
// word-bases of each scale's bitmap region (keyspace/32, rounded up to 64)
constexpr int kWB[5] = {0, 92736, 105152, 106944, 107264};
#define W_TOTAL 823552        // 107264 + 716288
#define SCAN_BLOCKS 403       // ceil(W_TOTAL / 2048)

// byte map = exact 32x expansion of the bit map: byte index = word*32 + bit.
#define BM_BYTES ((size_t)W_TOTAL * 32)     // 26,353,664 B
#define BM_U4    (BM_BYTES / 16)            // 1,647,104 uint4

// emit kernel block ranges (256 threads each)
#define SCAT_BLOCKS 3217    // ceil(W_TOTAL / 256)
#define PAD_BLOCKS  19532   // ceil(5*NPTS / 256)
#define INV_BLOCKS  3907    // ceil(NPTS / 256)
#define EMIT_BLOCKS (SCAT_BLOCKS + PAD_BLOCKS + INV_BLOCKS)

// ---- zero the byte map
__global__ void zero_kernel(uint4* __restrict__ p) {
  size_t i = (size_t)blockIdx.x * 256 + threadIdx.x;
  if (i < BM_U4) p[i] = make_uint4(0u, 0u, 0u, 0u);
}

// ---- mark: polar once per point; bxyz out; 5 idempotent byte stores
__global__ void mark_kernel(const float4* __restrict__ pts,
                            const int* __restrict__ bidx,
                            int* __restrict__ out,
                            unsigned char* __restrict__ bytemap) {
  int i = blockIdx.x * 256 + threadIdx.x;
  if (i >= NPTS) return;
  float4 p = pts[i];
  float rho = __fsqrt_rn(__fadd_rn(__fmul_rn(p.x, p.x), __fmul_rn(p.y, p.y)));
  float phi = (float)atan2((double)p.y, (double)p.x);
  float zz = p.z;
  int b = bidx[i];
  const float PI_F = 3.14159265f;
  const float CROP1 = PI_F + PI_F;
#pragma unroll
  for (int s = 0; s < 5; ++s) {
    int ix = (int)__fdiv_rn(__fmul_rn(kSSX[s], rho), 50.0f);
    int iy = (int)__fdiv_rn(__fmul_rn(kSSY[s], __fsub_rn(phi, -PI_F)), CROP1);
    int iz = (int)__fdiv_rn(__fmul_rn(kSSZ[s], __fsub_rn(zz, -4.0f)), 6.0f);
    int key = ((b * kSX[s] + ix) * kSY[s] + iy) * kSZ[s] + iz;
    ((int4*)(out + (size_t)s * OUT_STRIDE))[i] = make_int4(b, ix, iy, iz);
    bytemap[(size_t)kWB[s] * 32 + (unsigned)key] = 1;
  }
}

// 32 presence-bytes (each 0/1) -> 32-bit mask
__device__ __forceinline__ unsigned nib(unsigned u) {
  return (u | (u >> 7) | (u >> 14) | (u >> 21)) & 0xFu;
}
__device__ __forceinline__ unsigned word_from_bytes(const uint4* p) {
  uint4 a = p[0], b = p[1];
  return nib(a.x) | (nib(a.y) << 4) | (nib(a.z) << 8) | (nib(a.w) << 12) |
         (nib(b.x) << 16) | (nib(b.y) << 20) | (nib(b.z) << 24) | (nib(b.w) << 28);
}

// ---- scan stage 1: bytes -> {bits, block-local prefix} pairs + chunk sums
__global__ void scan1_kernel(const uint4* __restrict__ bytemap,
                             uint2* __restrict__ bw,
                             unsigned* __restrict__ bsums) {
  __shared__ unsigned sh[256];
  int tid = threadIdx.x;
  int base = blockIdx.x * 2048 + tid * 8;
  unsigned c[8], m[8];
  unsigned sum = 0;
#pragma unroll
  for (int j = 0; j < 8; ++j) {
    c[j] = sum;
    int w = base + j;
    m[j] = (w < W_TOTAL) ? word_from_bytes(bytemap + (size_t)w * 2) : 0u;
    sum += (unsigned)__popc(m[j]);
  }
  sh[tid] = sum;
  __syncthreads();
  for (int off = 1; off < 256; off <<= 1) {
    unsigned v = (tid >= off) ? sh[tid - off] : 0u;
    __syncthreads();
    sh[tid] += v;
    __syncthreads();
  }
  unsigned tbase = sh[tid] - sum;
#pragma unroll
  for (int j = 0; j < 8; ++j) {
    int w = base + j;
    if (w < W_TOTAL) bw[w] = make_uint2(m[j], tbase + c[j]);
  }
  if (tid == 0) bsums[blockIdx.x] = sh[255];
}

// ---- scan stage 2: exclusive scan of block sums; also store grand total
__global__ void scan2_kernel(unsigned* __restrict__ bsums) {
  __shared__ unsigned sh[1024];
  int t = threadIdx.x;
  unsigned v = (t < SCAN_BLOCKS) ? bsums[t] : 0u;
  sh[t] = v;
  __syncthreads();
  for (int off = 1; off < 1024; off <<= 1) {
    unsigned u = (t >= off) ? sh[t - off] : 0u;
    __syncthreads();
    sh[t] += u;
    __syncthreads();
  }
  if (t < SCAN_BLOCKS) bsums[t] = sh[t] - v;  // exclusive
  if (t == SCAN_BLOCKS - 1) bsums[512] = sh[t];  // inclusive grand total
}

// full prefix of word w = bw[w].y + bsums[w >> 11]
__device__ __forceinline__ unsigned fullp(const uint2* bw, const unsigned* bs, int w) {
  return bw[w].y + bs[w >> 11];
}

__device__ __forceinline__ unsigned region_count(int s, const uint2* bw,
                                                 const unsigned* bs) {
  unsigned lo = fullp(bw, bs, kWB[s]);
  unsigned hi = (s == 4) ? bs[512] : fullp(bw, bs, kWB[s + 1]);
  return hi - lo;
}

// ---- emit: fused scatter / padfill / inverse
__global__ void emit_kernel(const float4* __restrict__ pts,
                            const int* __restrict__ bidx,
                            const uint2* __restrict__ bw,
                            const unsigned* __restrict__ bsums,
                            int* __restrict__ out) {
  int blk = blockIdx.x;
  if (blk < SCAT_BLOCKS) {
    int w = blk * 256 + threadIdx.x;
    if (w >= W_TOTAL) return;
    uint2 v = bw[w];
    unsigned word = v.x;
    if (!word) return;
    int s, wb;
    unsigned sx, sy, sz;
    if      (w >= kWB[4]) { s = 4; wb = kWB[4]; sx = 481; sy = 361; sz = 33; }
    else if (w >= kWB[3]) { s = 3; wb = kWB[3]; sx = 31;  sy = 24;  sz = 3;  }
    else if (w >= kWB[2]) { s = 2; wb = kWB[2]; sx = 61;  sy = 46;  sz = 5;  }
    else if (w >= kWB[1]) { s = 1; wb = kWB[1]; sx = 121; sy = 91;  sz = 9;  }
    else                  { s = 0; wb = 0;      sx = 241; sy = 181; sz = 17; }
    unsigned rank = v.y + bsums[w >> 11] - fullp(bw, bsums, wb);
    int4* coors = (int4*)(out + (size_t)s * OUT_STRIDE + 5 * NPTS);
    unsigned kbase = (unsigned)(w - wb) * 32u;
    while (word) {
      int bit = __ffs(word) - 1;
      word &= word - 1;
      unsigned k = kbase + (unsigned)bit;
      unsigned z = k % sz; unsigned t = k / sz;
      unsigned y = t % sy; t /= sy;
      unsigned x = t % sx; unsigned b = t / sx;
      coors[rank++] = make_int4((int)b, (int)z, (int)y, (int)x);
    }
  } else if (blk < SCAT_BLOCKS + PAD_BLOCKS) {
    int idx = (blk - SCAT_BLOCKS) * 256 + threadIdx.x;
    if (idx >= 5 * NPTS) return;
    int s = idx / NPTS;
    int r = idx - s * NPTS;
    unsigned uniq = region_count(s, bw, bsums);
    if ((unsigned)r < uniq) return;
    ((int4*)(out + (size_t)s * OUT_STRIDE + 5 * NPTS))[r] =
        make_int4(-1, kSZ[s] - 1, kSY[s] - 1, kSX[s] - 1);
  } else {
    int i = (blk - SCAT_BLOCKS - PAD_BLOCKS) * 256 + threadIdx.x;
    if (i >= NPTS) return;
    float4 p = pts[i];
    float rho = __fsqrt_rn(__fadd_rn(__fmul_rn(p.x, p.x), __fmul_rn(p.y, p.y)));
    float phi = (float)atan2((double)p.y, (double)p.x);
    float zz = p.z;
    int b = bidx[i];
    const float PI_F = 3.14159265f;
    const float CROP1 = PI_F + PI_F;
#pragma unroll
    for (int s = 0; s < 5; ++s) {
      int ix = (int)__fdiv_rn(__fmul_rn(kSSX[s], rho), 50.0f);
      int iy = (int)__fdiv_rn(__fmul_rn(kSSY[s], __fsub_rn(phi, -PI_F)), CROP1);
      int iz = (int)__fdiv_rn(__fmul_rn(kSSZ[s], __fsub_rn(zz, -4.0f)), 6.0f);
      unsigned k = (unsigned)(((b * kSX[s] + ix) * kSY[s] + iy) * kSZ[s] + iz);
      int w = kWB[s] + (int)(k >> 5);
      uint2 v = bw[w];                       // one 8B gather: {bits, prefix}
      unsigned r = v.y + bsums[w >> 11] - fullp(bw, bsums, kWB[s]) +
                   (unsigned)__popc(v.x & ((1u << (k & 31)) - 1u));
      out[(size_t)s * OUT_STRIDE + 4 * NPTS + i] = (int)r;
    }
  }
}

extern "C" void kernel_launch(void* const* d_in, const int* in_sizes, int n_in,
                              void* d_out, int out_size, void* d_ws, size_t ws_size,
                              hipStream_t stream) {
  const float4* pts = (const float4*)d_in[0];
  const int* bidx = (const int*)d_in[1];
  int* out = (int*)d_out;

  uint2* bw       = (uint2*)d_ws;             // W_TOTAL uint2 (6.6 MB)
  unsigned* bsums = (unsigned*)(bw + W_TOTAL);  // 1024 u32 ([512] = grand total)
  unsigned char* bytemap = (unsigned char*)(bsums + 1024);  // 26.4 MB
  // total ws use: ~33 MB (proven available)

  zero_kernel<<<(int)((BM_U4 + 255) / 256), 256, 0, stream>>>((uint4*)bytemap);
  mark_kernel<<<(NPTS + 255) / 256, 256, 0, stream>>>(pts, bidx, out, bytemap);
  scan1_kernel<<<SCAN_BLOCKS, 256, 0, stream>>>((const uint4*)bytemap, bw, bsums);
  scan2_kernel<<<1, 1024, 0, stream>>>(bsums);
  emit_kernel<<<EMIT_BLOCKS, 256, 0, stream>>>(pts, bidx, bw, bsums, out);
}